// Round 10
// baseline (1158.326 us; speedup 1.0000x reference)
//
#include <hip/hip_runtime.h>
#include <hip/hip_fp16.h>
#include <stdint.h>

#define GLOBAL_AS __attribute__((address_space(1)))
#define LDS_AS    __attribute__((address_space(3)))

typedef __attribute__((ext_vector_type(8))) short  short8;   // 8 bf16 = 4 VGPRs
typedef __attribute__((ext_vector_type(4))) float  floatx4;

static constexpr int B_   = 4096;
static constexpr int T_   = 28;
static constexpr int IN_  = 28;
static constexpr int H_   = 1024;
static constexpr int G4_  = 4096;   // 4*H
static constexpr int OUT_ = 10;
static constexpr int NK_  = 32;     // K-tiles of 32 over H=1024

// ---------- small helpers ----------
__device__ __forceinline__ float bf2f(unsigned short u) {
  union { uint32_t i; float f; } v; v.i = ((uint32_t)u) << 16; return v.f;
}
__device__ __forceinline__ unsigned short f2bf(float f) {  // RTNE
  union { float f; uint32_t i; } v; v.f = f;
  uint32_t x = v.i;
  uint32_t lsb = (x >> 16) & 1u;
  x += 0x7fffu + lsb;
  return (unsigned short)(x >> 16);
}
__device__ __forceinline__ float sigm(float x) {
  return __builtin_amdgcn_rcpf(1.f + __builtin_amdgcn_exp2f(-1.4426950408889634f * x));
}
__device__ __forceinline__ float tanh_f(float x) {
  return 1.f - 2.f * __builtin_amdgcn_rcpf(1.f + __builtin_amdgcn_exp2f(2.8853900817779268f * x));
}
__device__ __forceinline__ void stage16(const unsigned short* g, unsigned short* l) {
  __builtin_amdgcn_global_load_lds(
      (const GLOBAL_AS uint32_t*)g, (LDS_AS uint32_t*)l, 16, 0, 0);
}

// ---------- prologue: x -> bf16 [T][B][32] (k padded 28->32 with zeros) ----------
__global__ __launch_bounds__(256) void conv_x_kernel(const float* __restrict__ x,
                                                     unsigned short* __restrict__ xb) {
  int row = blockIdx.x * 256 + threadIdx.x;   // row = t*4096 + b
  int t  = row >> 12;
  int bb = row & 4095;
  const float* src = x + (bb * T_ + t) * IN_;
  unsigned short* dst = xb + row * 32;
#pragma unroll
  for (int k = 0; k < IN_; ++k) dst[k] = f2bf(src[k]);
  dst[28] = 0; dst[29] = 0; dst[30] = 0; dst[31] = 0;
}

// ---------- prologue: W_hh [1024][4096] fp32 -> Wp [4096][1024] bf16, transposed+interleaved ----------
// permuted n = g64*64 + gate*16 + hw  <->  orig col = gate*1024 + g64*16 + hw
__global__ __launch_bounds__(256) void perm_whh_kernel(const float* __restrict__ whh,
                                                       unsigned short* __restrict__ wp) {
  __shared__ float lds[64][17];
  int g64  = blockIdx.x >> 2;
  int gate = blockIdx.x & 3;
  int oc0  = gate * H_ + g64 * 16;
  int n0   = g64 * 64 + gate * 16;
  int tid  = threadIdx.x;
  for (int kc = 0; kc < 16; ++kc) {
    int k0 = kc * 64;
    __syncthreads();
#pragma unroll
    for (int e = 0; e < 4; ++e) {
      int idx = e * 256 + tid;
      int k = idx >> 4, cc = idx & 15;
      lds[k][cc] = whh[(k0 + k) * G4_ + oc0 + cc];
    }
    __syncthreads();
#pragma unroll
    for (int e = 0; e < 4; ++e) {
      int idx = e * 256 + tid;
      int n = idx >> 6, kk = idx & 63;
      wp[(n0 + n) * H_ + k0 + kk] = f2bf(lds[kk][n]);
    }
  }
}

// ---------- prologue: W_ih [28][4096] -> Wip [4096][32] bf16 transposed+interleaved ----------
__global__ __launch_bounds__(256) void perm_wih_kernel(const float* __restrict__ wih,
                                                       unsigned short* __restrict__ wip) {
  __shared__ float lds[28][17];
  int g64  = blockIdx.x >> 2;
  int gate = blockIdx.x & 3;
  int oc0  = gate * H_ + g64 * 16;
  int n0   = g64 * 64 + gate * 16;
  int tid  = threadIdx.x;
  for (int idx = tid; idx < 448; idx += 256) {
    int k = idx >> 4, cc = idx & 15;
    lds[k][cc] = wih[k * G4_ + oc0 + cc];
  }
  __syncthreads();
#pragma unroll
  for (int e = 0; e < 2; ++e) {
    int idx = e * 256 + tid;
    int n = idx >> 5, kk = idx & 31;
    wip[(n0 + n) * 32 + kk] = (kk < IN_) ? f2bf(lds[kk][n]) : (unsigned short)0;
  }
}

// ====== LSTM step: 256x128 tile, BK=32, 3-deep LDS ring (72 KB), 2 blocks/CU ======
// 8 waves (4M x 2N), wave-tile 64x64. Per tile: ONE barrier, stage tile kt+2 (3 gload_lds),
// counted vmcnt(6) (2-tile prefetch depth, never 0 mid-loop), 8 ds_read_b128, 16 MFMA.
// WAR: stage@kt overwrites tile kt-1's buffer; its reads were consumed before BAR_kt.
// Bank swizzle for 64-B rows: slot ^= ((row>>1)&3)<<4 (2-way = free); pre-swizzled source.
// x-projection tile == main-tile layout in buf0 (same LOAD/MFMA macros). c-state fp16.
__global__ __launch_bounds__(512, 4) void lstm_step_kernel(
    const unsigned short* __restrict__ hprev,   // [B][H] bf16
    const unsigned short* __restrict__ wp,      // [4096][1024] bf16 (permuted^T)
    const unsigned short* __restrict__ xbt,     // [B][32] bf16 (this t)
    const unsigned short* __restrict__ wip,     // [4096][32] bf16 (permuted^T)
    const float* __restrict__ bias,             // [4096] original gate order
    unsigned short* __restrict__ cst,           // [B][H] fp16 cell state
    unsigned short* __restrict__ hnext,         // [B][H] bf16
    int first) {
  __shared__ __align__(16) unsigned short lds[36864];   // 72 KB = 3 x 24 KB (A 16K | B 8K)

  const int tid = threadIdx.x;           // 0..511
  const int w   = tid >> 6;              // wave 0..7
  const int l   = tid & 63;
  const int wm  = w >> 1;                // 0..3  (M quarter, 64 rows)
  const int wn  = w & 1;                 // 0..1  (N half, 64 cols)
  const int lc  = l & 15;
  const int lk  = l >> 4;                // 0..3

  // XCD-aware swizzle: 8x8 (bx,by) rectangle per XCD (bijective, 512 = 8 XCD * 64)
  const int hid = blockIdx.x;
  const int xcd = hid & 7, q = hid >> 3;           // q 0..63
  const int bx  = (xcd & 1) * 8 + (q & 7);         // 0..15
  const int by  = (xcd >> 1) * 8 + (q >> 3);       // 0..31
  const int m0  = bx * 256;              // batch rows
  const int n0  = by * 128;              // permuted gate cols

  const int sl = (lk * 16) ^ (((lc >> 1) & 3) << 4);   // ds_read slot within 64-B row

  // ---- staging per-thread constants: chunk = 128 rows x 32 cols (8 KB) ----
  const int r4 = tid >> 2;                             // chunk row 0..127
  const int cs = ((tid & 3) * 8) ^ (((r4 >> 1) & 3) * 8);  // pre-swizzled ushort col

  auto stageA = [&](int bufU, int kt, int i) {   // A chunk i: rows i*128..., 4096 u each
    stage16(hprev + (size_t)(m0 + i * 128 + r4) * H_ + kt * 32 + cs,
            lds + bufU + i * 4096 + tid * 8);
  };
  auto stageB = [&](int bufU, int kt) {          // B: 128 rows, at +8192 u
    stage16(wp + (size_t)(n0 + r4) * H_ + kt * 32 + cs,
            lds + bufU + 8192 + tid * 8);
  };
  auto stageXA = [&](int i) {
    stage16(xbt + (size_t)(m0 + i * 128 + r4) * 32 + cs, lds + i * 4096 + tid * 8);
  };
  auto stageXB = [&]() {
    stage16(wip + (size_t)(n0 + r4) * 32 + cs, lds + 8192 + tid * 8);
  };
  auto ldsr = [&](int byteoff) -> short8 {
    return *reinterpret_cast<const short8*>(reinterpret_cast<const char*>(lds) + byteoff);
  };

  floatx4 acc[4][4];                     // 64 VGPR
#pragma unroll
  for (int i = 0; i < 4; ++i)
#pragma unroll
    for (int j = 0; j < 4; ++j) acc[i][j] = (floatx4){0.f, 0.f, 0.f, 0.f};

  short8 a[4];                           // 16 VGPR
  short8 b[4];                           // 16 VGPR

#define LOAD_AB(PB)                                                                  \
  _Pragma("unroll") for (int m_ = 0; m_ < 4; ++m_)                                   \
    a[m_] = ldsr((PB) + (wm * 64 + m_ * 16 + lc) * 64 + sl);                         \
  _Pragma("unroll") for (int n_ = 0; n_ < 4; ++n_)                                   \
    b[n_] = ldsr((PB) + 16384 + (wn * 64 + n_ * 16 + lc) * 64 + sl);

#define MFMA_T                                                                       \
  __builtin_amdgcn_s_setprio(1);                                                     \
  _Pragma("unroll") for (int m_ = 0; m_ < 4; ++m_)                                   \
  _Pragma("unroll") for (int n_ = 0; n_ < 4; ++n_)                                   \
    acc[m_][n_] = __builtin_amdgcn_mfma_f32_16x16x32_bf16(                           \
        a[m_], b[n_], acc[m_][n_], 0, 0, 0);                                         \
  __builtin_amdgcn_s_setprio(0);

#define BAR                                                                          \
  __builtin_amdgcn_sched_barrier(0);                                                 \
  __builtin_amdgcn_s_barrier();                                                      \
  __builtin_amdgcn_sched_barrier(0);

#define WAITV(VM)                                                                    \
  asm volatile("s_waitcnt vmcnt(" #VM ")" ::: "memory");                             \
  __builtin_amdgcn_sched_barrier(0);

  // ring: tile kt lives in buf[(kt+1)%3]; x in buf0. ushort bases: 0 / 12288 / 24576.
  if (first) {
    stageXA(0); stageXA(1); stageXB();
    WAITV(0)
    BAR
    LOAD_AB(0)
    MFMA_T
  } else {
    // prologue: x -> buf0, t0 -> buf1, t1 -> buf2  (9 chunks in flight)
    stageXA(0); stageXA(1); stageXB();
    stageA(12288, 0, 0); stageA(12288, 0, 1); stageB(12288, 0);
    stageA(24576, 1, 0); stageA(24576, 1, 1); stageB(24576, 1);
    WAITV(6)                                   // x landed; t0,t1 in flight
    BAR
    LOAD_AB(0)                                 // x tile (layout-identical)
    MFMA_T

    // ---- main loop: 32 K-tiles, unrolled x3 for static ring indices ----
#define ITER(KT, RDB, WRB)                                                           \
    BAR                                                                              \
    if ((KT) + 2 < NK_) {                                                            \
      stageA((WRB), (KT) + 2, 0); stageA((WRB), (KT) + 2, 1); stageB((WRB), (KT) + 2); \
      WAITV(6)                                                                       \
    } else if ((KT) + 2 == NK_) { WAITV(3) } else { WAITV(0) }                       \
    LOAD_AB((RDB) * 2)                                                               \
    MFMA_T

    for (int kt = 0; kt < 30; kt += 3) {
      ITER(kt,     12288, 0)        // read buf1, stage -> buf0
      ITER(kt + 1, 24576, 12288)    // read buf2, stage -> buf1
      ITER(kt + 2, 0,     24576)    // read buf0, stage -> buf2
    }
    ITER(30, 12288, 0)              // kt=30: no stage (kt+2==32 -> vmcnt(3))
    ITER(31, 24576, 12288)          // kt=31: vmcnt(0)
#undef ITER
  }

  // ---- epilogue: frag nf == gate; fused LSTM cell update; c in fp16 ----
  const int jj  = (by * 2 + wn) * 16 + lc;     // h column 0..1023
  const float bi  = bias[jj];
  const float bf_ = bias[H_ + jj];
  const float bg_ = bias[2 * H_ + jj];
  const float bo_ = bias[3 * H_ + jj];
#pragma unroll
  for (int mf = 0; mf < 4; ++mf) {
    const int rbase = m0 + wm * 64 + mf * 16 + lk * 4;
#pragma unroll
    for (int r = 0; r < 4; ++r) {
      const size_t idx = (size_t)(rbase + r) * H_ + jj;
      float ig = sigm(acc[mf][0][r] + bi);
      float fg = sigm(acc[mf][1][r] + bf_);
      float gg = tanh_f(acc[mf][2][r] + bg_);
      float og = sigm(acc[mf][3][r] + bo_);
      float cp = first ? 0.f : __half2float(__ushort_as_half(cst[idx]));
      float cn = fg * cp + ig * gg;
      cst[idx] = __half_as_ushort(__float2half(cn));
      hnext[idx] = f2bf(og * tanh_f(cn));
    }
  }
#undef LOAD_AB
#undef MFMA_T
#undef BAR
#undef WAITV
}

// ---------- classifier: out = h @ Wc + bc ----------
__global__ __launch_bounds__(256) void cls_kernel(const unsigned short* __restrict__ h,
                                                  const float* __restrict__ wc,
                                                  const float* __restrict__ bc,
                                                  float* __restrict__ out) {
  int w = threadIdx.x >> 6, l = threadIdx.x & 63;
  int row = blockIdx.x * 4 + w;
  float acc[OUT_];
#pragma unroll
  for (int o = 0; o < OUT_; ++o) acc[o] = 0.f;
  const unsigned short* hr = h + row * H_;
  for (int k = l; k < H_; k += 64) {
    float hv = bf2f(hr[k]);
#pragma unroll
    for (int o = 0; o < OUT_; ++o) acc[o] += hv * wc[k * OUT_ + o];
  }
#pragma unroll
  for (int o = 0; o < OUT_; ++o) {
    float v = acc[o];
#pragma unroll
    for (int s = 32; s > 0; s >>= 1) v += __shfl_down(v, s, 64);
    if (l == 0) out[row * OUT_ + o] = v + bc[o];
  }
}

extern "C" void kernel_launch(void* const* d_in, const int* in_sizes, int n_in,
                              void* d_out, int out_size, void* d_ws, size_t ws_size,
                              hipStream_t stream) {
  const float* x    = (const float*)d_in[0];
  const float* wih  = (const float*)d_in[1];
  const float* whh  = (const float*)d_in[2];
  const float* bias = (const float*)d_in[3];
  const float* wc   = (const float*)d_in[4];
  const float* bc   = (const float*)d_in[5];
  float* out = (float*)d_out;

  char* ws = (char*)d_ws;
  unsigned short* wp  = (unsigned short*)(ws);                 //  8 MB  permuted W_hh^T bf16
  unsigned short* wip = (unsigned short*)(ws + 8388608);       //  256KB permuted W_ih^T bf16
  unsigned short* xb  = (unsigned short*)(ws + 8650752);       //  7 MB  x bf16 [T][B][32]
  unsigned short* h0  = (unsigned short*)(ws + 15990784);      //  8 MB
  unsigned short* h1  = (unsigned short*)(ws + 24379392);      //  8 MB
  unsigned short* cst = (unsigned short*)(ws + 32768000);      //  8 MB  fp16 cell state

  hipLaunchKernelGGL(conv_x_kernel,  dim3(448), dim3(256), 0, stream, x, xb);
  hipLaunchKernelGGL(perm_whh_kernel, dim3(256), dim3(256), 0, stream, whh, wp);
  hipLaunchKernelGGL(perm_wih_kernel, dim3(256), dim3(256), 0, stream, wih, wip);

  unsigned short* hb[2] = {h0, h1};
  for (int t = 0; t < T_; ++t) {
    unsigned short* hn = hb[t & 1];
    unsigned short* hp = hb[(t & 1) ^ 1];
    hipLaunchKernelGGL(lstm_step_kernel, dim3(512), dim3(512), 0, stream,
                       hp, wp, xb + (size_t)t * (B_ * 32), wip, bias, cst, hn,
                       (t == 0) ? 1 : 0);
  }
  hipLaunchKernelGGL(cls_kernel, dim3(1024), dim3(256), 0, stream, hb[1], wc, bc, out);
}